// Round 1
// 1112.296 us; speedup vs baseline: 1.0947x; 1.0947x over previous
//
#include <hip/hip_runtime.h>
#include <math.h>

typedef unsigned short u16;
typedef float v4f __attribute__((ext_vector_type(4)));
typedef short v8s __attribute__((ext_vector_type(8)));

// ---------- helpers ----------
__device__ __forceinline__ u16 f2bf(float f) {
  union { float f; unsigned u; } c; c.f = f;
  unsigned u = c.u;
  u += 0x7fff + ((u >> 16) & 1);   // RNE
  return (u16)(u >> 16);
}

// async global->LDS, 16B per lane, dest = wave-uniform base + lane*16
typedef __attribute__((address_space(1))) const unsigned int guint;
typedef __attribute__((address_space(3))) unsigned int luint;
__device__ __forceinline__ void gll16(const void* g, void* l) {
  __builtin_amdgcn_global_load_lds((guint*)g, (luint*)l, 16, 0, 0);
}

// window-row r (win*64+n, shifted frame) -> natural token index.
__device__ __forceinline__ int row_to_token(int r) {
  int win = r >> 6, n = r & 63;
  int b = (win >= 784) ? 1 : 0;
  int wrem = win - b * 784;
  int wd = wrem / 196;
  int r2 = wrem - wd * 196;
  int wh = r2 / 14;
  int ww = r2 - wh * 14;
  int d = wd * 4 + (n >> 4);
  int h = wh * 4 + ((n >> 2) & 3);
  int w = ww * 4 + (n & 3);
  d = (d + 2) & 15;
  h += 2; if (h >= 56) h -= 56;
  w += 2; if (w >= 56) w -= 56;
  return ((b * 16 + d) * 56 + h) * 56 + w;
}

__device__ __forceinline__ int region_label(int n, int bd, int bh, int bw) {
  int ld = bd ? (((n >> 4) >= 2) ? 2 : 1) : 0;
  int lh = bh ? ((((n >> 2) & 3) >= 2) ? 2 : 1) : 0;
  int lw = bw ? (((n & 3) >= 2) ? 2 : 1) : 0;
  return ld * 9 + lh * 3 + lw;
}

// ---------- weight transpose + bf16 convert: src f32 [K][N] -> dst bf16 [N][K] ----------
__global__ __launch_bounds__(256) void transpose_w(const float* __restrict__ src, u16* __restrict__ dst,
                                                   int K, int N) {
  __shared__ u16 t[32][33];
  int kt = blockIdx.x * 32, nt = blockIdx.y * 32;
  int lx = threadIdx.x & 31, ly = threadIdx.x >> 5;   // 8 rows/pass
#pragma unroll
  for (int i = 0; i < 32; i += 8)
    t[ly + i][lx] = f2bf(src[(size_t)(kt + ly + i) * N + nt + lx]);
  __syncthreads();
#pragma unroll
  for (int i = 0; i < 32; i += 8)
    dst[(size_t)(nt + ly + i) * K + kt + lx] = t[lx][ly + i];
}

__global__ __launch_bounds__(256) void bias_kernel(const float* __restrict__ rpb, float* __restrict__ biasb) {
  int i = blockIdx.x * 256 + threadIdx.x;   // 49152 = 12*64*64, layout [h][n][m]
  int h = i >> 12, n = (i >> 6) & 63, m = i & 63;
  int dd = (n >> 4) - (m >> 4) + 3;
  int dh = ((n >> 2) & 3) - ((m >> 2) & 3) + 3;
  int dw = (n & 3) - (m & 3) + 3;
  biasb[i] = rpb[(dd * 49 + dh * 7 + dw) * 12 + h];
}

// ---------- LayerNorm (one wave per token row) ----------
template<bool MAP>
__global__ __launch_bounds__(256) void ln_kernel(const float* __restrict__ x, const float* __restrict__ g,
                                                 const float* __restrict__ bta, u16* __restrict__ out) {
  int wid = threadIdx.x >> 6, lane = threadIdx.x & 63;
  int r = blockIdx.x * 4 + wid;
  int t = MAP ? row_to_token(r) : r;
  const float* src = x + (size_t)t * 384;
  float v[6]; float s = 0.f;
#pragma unroll
  for (int i = 0; i < 6; i++) { v[i] = src[lane + i * 64]; s += v[i]; }
#pragma unroll
  for (int off = 1; off < 64; off <<= 1) s += __shfl_xor(s, off);
  float mu = s * (1.f / 384.f);
  float vs = 0.f;
#pragma unroll
  for (int i = 0; i < 6; i++) { float d = v[i] - mu; vs += d * d; }
#pragma unroll
  for (int off = 1; off < 64; off <<= 1) vs += __shfl_xor(vs, off);
  float rstd = 1.f / sqrtf(vs * (1.f / 384.f) + 1e-5f);
  u16* dst = out + (size_t)r * 384;
#pragma unroll
  for (int i = 0; i < 6; i++) {
    int c = lane + i * 64;
    dst[c] = f2bf((v[i] - mu) * rstd * g[c] + bta[c]);
  }
}

// ---------- GEMM: 128x128 tile, BK=32, 4 waves, 16x16x32 bf16 MFMA ----------
// m97-style staging: global_load_lds width-16 into LINEAR LDS; 16B-slot XOR
// swizzle (phys_slot = slot ^ ((row>>1)&3)) applied to BOTH the global source
// and the ds_read side -> conflict-free ds_read_b128 (rule 21 involution).
// 1-D grid with bijective XCD swizzle (all nwg are multiples of 8).
// A: [M][K] bf16.  Bw: [N][K] bf16 (pre-transposed).
// EPI: 0=qkv(bias->bf16)  1=proj(bias + scatter + shortcut -> f32 out)
//      2=fc1(bias+gelu->bf16)  3=fc2(bias, += out f32)
template<int EPI>
__global__ __launch_bounds__(256) void gemm_bf16(const u16* __restrict__ A, const u16* __restrict__ Bw,
                                                 const float* __restrict__ bias, int N, int K,
                                                 u16* __restrict__ out_bf, float* __restrict__ out_f,
                                                 const float* __restrict__ resid, int ntn) {
  __shared__ __align__(16) u16 As[4096];   // 128 rows x 32 cols, slot-swizzled
  __shared__ __align__(16) u16 Bs[4096];
  const int tid = threadIdx.x;
  const int nwg = gridDim.x;
  const int bid = blockIdx.x;
  const int swz = (bid & 7) * (nwg >> 3) + (bid >> 3);   // XCD-chunked, bijective (nwg%8==0)
  const int by = swz / ntn;
  const int bx = swz - by * ntn;
  const int m0 = by * 128, n0 = bx * 128;
  const int wid = tid >> 6, lane = tid & 63;
  const int wm = (wid >> 1) * 64, wn = (wid & 1) * 64;
  const int l15 = lane & 15, q4 = lane >> 4;

  // staging: round i covers phys LDS bytes [i*4096 + tid*16, +16)
  // u = i*256 + tid; phys row = u>>2; logical slot = (u&3) ^ ((row>>1)&3)
  const int u0 = tid, u1 = 256 + tid;
  const int r0 = u0 >> 2, r1 = u1 >> 2;
  const int c0 = ((u0 & 3) ^ ((r0 >> 1) & 3)) << 3;   // u16 col offset
  const int c1 = ((u1 & 3) ^ ((r1 >> 1) & 3)) << 3;
  const u16* ag0 = A + (size_t)(m0 + r0) * K + c0;
  const u16* ag1 = A + (size_t)(m0 + r1) * K + c1;
  const u16* bg0 = Bw + (size_t)(n0 + r0) * K + c0;
  const u16* bg1 = Bw + (size_t)(n0 + r1) * K + c1;
  u16* asd0 = As + (wid << 9);          // wave-uniform LDS dests (1KB/wave/round)
  u16* asd1 = As + 2048 + (wid << 9);
  u16* bsd0 = Bs + (wid << 9);
  u16* bsd1 = Bs + 2048 + (wid << 9);

  // swizzled fragment-read byte offsets
  int aoff[4], boff[4];
#pragma unroll
  for (int t = 0; t < 4; t++) {
    int ra = wm + t * 16 + l15;
    aoff[t] = ra * 64 + ((q4 ^ ((ra >> 1) & 3)) << 4);
    int rb = wn + t * 16 + l15;
    boff[t] = rb * 64 + ((q4 ^ ((rb >> 1) & 3)) << 4);
  }

  v4f acc[4][4];
#pragma unroll
  for (int i = 0; i < 4; i++)
#pragma unroll
    for (int j = 0; j < 4; j++) acc[i][j] = (v4f){0.f, 0.f, 0.f, 0.f};

  // prologue: stage k-tile 0
  gll16(ag0, asd0); gll16(ag1, asd1);
  gll16(bg0, bsd0); gll16(bg1, bsd1);
  ag0 += 32; ag1 += 32; bg0 += 32; bg1 += 32;

  const int nk = K >> 5;
  for (int kk = 0; kk < nk; ++kk) {
    __syncthreads();                       // staged tile visible (vmcnt drain)
    v8s afr[4], bfr[4];
#pragma unroll
    for (int t = 0; t < 4; t++) {
      afr[t] = *(const v8s*)((const char*)As + aoff[t]);
      bfr[t] = *(const v8s*)((const char*)Bs + boff[t]);
    }
    __syncthreads();                       // all waves done reading LDS
    if (kk + 1 < nk) {                     // stage next tile; lands during MFMA
      gll16(ag0, asd0); gll16(ag1, asd1);
      gll16(bg0, bsd0); gll16(bg1, bsd1);
      ag0 += 32; ag1 += 32; bg0 += 32; bg1 += 32;
    }
#pragma unroll
    for (int tm = 0; tm < 4; tm++)
#pragma unroll
      for (int tn = 0; tn < 4; tn++)
        acc[tm][tn] = __builtin_amdgcn_mfma_f32_16x16x32_bf16(afr[tm], bfr[tn], acc[tm][tn], 0, 0, 0);
  }

  // epilogue
  float bb[4]; int gc[4];
#pragma unroll
  for (int tn = 0; tn < 4; tn++) { gc[tn] = n0 + wn + tn * 16 + l15; bb[tn] = bias[gc[tn]]; }
#pragma unroll
  for (int tm = 0; tm < 4; tm++) {
#pragma unroll
    for (int r = 0; r < 4; r++) {
      const int grow = m0 + wm + tm * 16 + q4 * 4 + r;
      size_t rowbase;
      if constexpr (EPI == 1) rowbase = (size_t)row_to_token(grow) * 384;
      else rowbase = (size_t)grow * N;
#pragma unroll
      for (int tn = 0; tn < 4; tn++) {
        float val = acc[tm][tn][r] + bb[tn];
        if constexpr (EPI == 0) {
          out_bf[rowbase + gc[tn]] = f2bf(val);
        } else if constexpr (EPI == 2) {
          val = 0.5f * val * (1.f + erff(val * 0.70710678118654752f));
          out_bf[rowbase + gc[tn]] = f2bf(val);
        } else if constexpr (EPI == 1) {
          out_f[rowbase + gc[tn]] = resid[rowbase + gc[tn]] + val;
        } else {
          out_f[rowbase + gc[tn]] += val;
        }
      }
    }
  }
}

// ---------- attention: one wave per (window, head) ----------
__global__ __launch_bounds__(256) void attn_kernel(const u16* __restrict__ qkv, const float* __restrict__ biasb,
                                                   u16* __restrict__ outb) {
  __shared__ u16 P[4][64][72];              // per-wave P tile, bf16, padded
  int wid = threadIdx.x >> 6, lane = threadIdx.x & 63;
  int g = blockIdx.x * 4 + wid;
  int win = g / 12, head = g - win * 12;
  int l15 = lane & 15, q4 = lane >> 4;
  const u16* base = qkv + (size_t)win * 64 * 1152;
  const u16* qp = base + head * 32;
  const u16* kp = base + 384 + head * 32;
  const u16* vp = base + 768 + head * 32;

  v8s a[4], kb[4];
#pragma unroll
  for (int tm = 0; tm < 4; tm++) a[tm] = *(const v8s*)(qp + (size_t)(tm * 16 + l15) * 1152 + q4 * 8);
#pragma unroll
  for (int tn = 0; tn < 4; tn++) kb[tn] = *(const v8s*)(kp + (size_t)(tn * 16 + l15) * 1152 + q4 * 8);
  v4f acc[4][4];
#pragma unroll
  for (int i = 0; i < 4; i++)
#pragma unroll
    for (int j = 0; j < 4; j++) acc[i][j] = (v4f){0.f, 0.f, 0.f, 0.f};
#pragma unroll
  for (int tm = 0; tm < 4; tm++)
#pragma unroll
    for (int tn = 0; tn < 4; tn++)
      acc[tm][tn] = __builtin_amdgcn_mfma_f32_16x16x32_bf16(a[tm], kb[tn], acc[tm][tn], 0, 0, 0);

  int wrem = win % 784;
  int wd = wrem / 196, r2 = wrem % 196, wh = r2 / 14, ww = r2 % 14;
  int bd = (wd == 3), bh = (wh == 13), bw = (ww == 13);
  const float* bptr = biasb + head * 4096;
  int mlab[4];
#pragma unroll
  for (int tn = 0; tn < 4; tn++) mlab[tn] = region_label(tn * 16 + l15, bd, bh, bw);

#pragma unroll
  for (int tm = 0; tm < 4; tm++) {
#pragma unroll
    for (int r = 0; r < 4; r++) {
      int n = tm * 16 + q4 * 4 + r;
      int nlab = region_label(n, bd, bh, bw);
      float sv[4];
      float mx = -1e30f;
#pragma unroll
      for (int tn = 0; tn < 4; tn++) {
        int m = tn * 16 + l15;
        float s = acc[tm][tn][r] * 0.17677669529663687f + bptr[n * 64 + m];
        if (mlab[tn] != nlab) s -= 100.f;
        sv[tn] = s;
        mx = fmaxf(mx, s);
      }
#pragma unroll
      for (int off = 1; off < 16; off <<= 1) mx = fmaxf(mx, __shfl_xor(mx, off));
      float sum = 0.f;
#pragma unroll
      for (int tn = 0; tn < 4; tn++) { float e = __expf(sv[tn] - mx); sv[tn] = e; sum += e; }
#pragma unroll
      for (int off = 1; off < 16; off <<= 1) sum += __shfl_xor(sum, off);
      float inv = 1.f / sum;
#pragma unroll
      for (int tn = 0; tn < 4; tn++) P[wid][n][tn * 16 + l15] = f2bf(sv[tn] * inv);
    }
  }
  __syncthreads();   // C-layout -> A-layout via LDS

  v4f o[4][2];
#pragma unroll
  for (int i = 0; i < 4; i++) { o[i][0] = (v4f){0.f,0.f,0.f,0.f}; o[i][1] = (v4f){0.f,0.f,0.f,0.f}; }
#pragma unroll
  for (int kt = 0; kt < 2; kt++) {
    v8s pa[4];
#pragma unroll
    for (int tm = 0; tm < 4; tm++) pa[tm] = *(const v8s*)&P[wid][tm * 16 + l15][kt * 32 + q4 * 8];
#pragma unroll
    for (int tn = 0; tn < 2; tn++) {
      v8s vb;
#pragma unroll
      for (int j = 0; j < 8; j++) vb[j] = (short)vp[(size_t)(kt * 32 + q4 * 8 + j) * 1152 + tn * 16 + l15];
#pragma unroll
      for (int tm = 0; tm < 4; tm++)
        o[tm][tn] = __builtin_amdgcn_mfma_f32_16x16x32_bf16(pa[tm], vb, o[tm][tn], 0, 0, 0);
    }
  }
#pragma unroll
  for (int tm = 0; tm < 4; tm++)
#pragma unroll
    for (int tn = 0; tn < 2; tn++)
#pragma unroll
      for (int r = 0; r < 4; r++) {
        int n = tm * 16 + q4 * 4 + r;
        outb[(size_t)(win * 64 + n) * 384 + head * 32 + tn * 16 + l15] = f2bf(o[tm][tn][r]);
      }
}

// ---------- launch ----------
extern "C" void kernel_launch(void* const* d_in, const int* in_sizes, int n_in,
                              void* d_out, int out_size, void* d_ws, size_t ws_size,
                              hipStream_t stream) {
  const float* x      = (const float*)d_in[0];
  const float* n1g    = (const float*)d_in[1];
  const float* n1b    = (const float*)d_in[2];
  const float* qkv_w  = (const float*)d_in[3];
  const float* qkv_b  = (const float*)d_in[4];
  const float* rpb    = (const float*)d_in[5];
  const float* proj_w = (const float*)d_in[6];
  const float* proj_b = (const float*)d_in[7];
  const float* n2g    = (const float*)d_in[8];
  const float* n2b    = (const float*)d_in[9];
  const float* fc1_w  = (const float*)d_in[10];
  const float* fc1_b  = (const float*)d_in[11];
  const float* fc2_w  = (const float*)d_in[12];
  const float* fc2_b  = (const float*)d_in[13];
  float* out = (float*)d_out;
  char* ws = (char*)d_ws;

  // workspace layout (bytes): weights_bf16(T) | attn_bias | lnbuf | [qkv | attn_out] / fc1_out
  u16*   wb    = (u16*)ws;                        // 1769472 el
  float* biasb = (float*)(ws + 3538944);          // 49152 f32
  u16*   lnbuf = (u16*)(ws + 3735552);            // 100352*384
  u16*   qkvb  = (u16*)(ws + 80805888);           // 100352*1152
  u16*   attnb = (u16*)(ws + 312016896);          // 100352*384
  u16*   fc1ob = (u16*)(ws + 80805888);           // 100352*1536 (aliases dead qkvb+attnb)

  u16* qkv_wt  = wb;                  // [1152][384]
  u16* proj_wt = wb + 442368;         // [384][384]
  u16* fc1_wt  = wb + 589824;         // [1536][384]
  u16* fc2_wt  = wb + 1179648;        // [384][1536]

  transpose_w<<<dim3(12, 36), 256, 0, stream>>>(qkv_w,  qkv_wt,  384, 1152);
  transpose_w<<<dim3(12, 12), 256, 0, stream>>>(proj_w, proj_wt, 384, 384);
  transpose_w<<<dim3(12, 48), 256, 0, stream>>>(fc1_w,  fc1_wt,  384, 1536);
  transpose_w<<<dim3(48, 12), 256, 0, stream>>>(fc2_w,  fc2_wt,  1536, 384);
  bias_kernel<<<192, 256, 0, stream>>>(rpb, biasb);
  ln_kernel<true><<<25088, 256, 0, stream>>>(x, n1g, n1b, lnbuf);
  gemm_bf16<0><<<dim3(9 * 784), 256, 0, stream>>>(lnbuf, qkv_wt, qkv_b, 1152, 384, qkvb, nullptr, nullptr, 9);
  attn_kernel<<<4704, 256, 0, stream>>>(qkvb, biasb, attnb);
  gemm_bf16<1><<<dim3(3 * 784), 256, 0, stream>>>(attnb, proj_wt, proj_b, 384, 384, nullptr, out, x, 3);
  ln_kernel<false><<<25088, 256, 0, stream>>>(out, n2g, n2b, lnbuf);
  gemm_bf16<2><<<dim3(12 * 784), 256, 0, stream>>>(lnbuf, fc1_wt, fc1_b, 1536, 384, fc1ob, nullptr, nullptr, 12);
  gemm_bf16<3><<<dim3(3 * 784), 256, 0, stream>>>(fc1ob, fc2_wt, fc2_b, 384, 1536, nullptr, out, nullptr, 3);
}

// Round 2
// 1082.683 us; speedup vs baseline: 1.1246x; 1.0274x over previous
//
#include <hip/hip_runtime.h>
#include <math.h>

typedef unsigned short u16;
typedef float v4f __attribute__((ext_vector_type(4)));
typedef short v8s __attribute__((ext_vector_type(8)));

// ---------- helpers ----------
__device__ __forceinline__ u16 f2bf(float f) {
  union { float f; unsigned u; } c; c.f = f;
  unsigned u = c.u;
  u += 0x7fff + ((u >> 16) & 1);   // RNE
  return (u16)(u >> 16);
}

// fast GELU: x * sigmoid(2c(x + 0.044715 x^3)), c = sqrt(2/pi), via exp2/rcp HW units.
// constants pre-multiplied by log2(e). Max dev from exact erf-GELU ~2e-4.
__device__ __forceinline__ float fast_gelu(float x) {
  float t = x * x;
  float u = x * (2.3022082f + 0.10294325f * t);
  float e = __builtin_amdgcn_exp2f(-u);
  return x * __builtin_amdgcn_rcpf(1.f + e);
}

// async global->LDS, 16B per lane, dest = wave-uniform base + lane*16
typedef __attribute__((address_space(1))) const unsigned int guint;
typedef __attribute__((address_space(3))) unsigned int luint;
__device__ __forceinline__ void gll16(const void* g, void* l) {
  __builtin_amdgcn_global_load_lds((guint*)g, (luint*)l, 16, 0, 0);
}

// window-row r (win*64+n, shifted frame) -> natural token index.
__device__ __forceinline__ int row_to_token(int r) {
  int win = r >> 6, n = r & 63;
  int b = (win >= 784) ? 1 : 0;
  int wrem = win - b * 784;
  int wd = wrem / 196;
  int r2 = wrem - wd * 196;
  int wh = r2 / 14;
  int ww = r2 - wh * 14;
  int d = wd * 4 + (n >> 4);
  int h = wh * 4 + ((n >> 2) & 3);
  int w = ww * 4 + (n & 3);
  d = (d + 2) & 15;
  h += 2; if (h >= 56) h -= 56;
  w += 2; if (w >= 56) w -= 56;
  return ((b * 16 + d) * 56 + h) * 56 + w;
}

__device__ __forceinline__ int region_label(int n, int bd, int bh, int bw) {
  int ld = bd ? (((n >> 4) >= 2) ? 2 : 1) : 0;
  int lh = bh ? ((((n >> 2) & 3) >= 2) ? 2 : 1) : 0;
  int lw = bw ? (((n & 3) >= 2) ? 2 : 1) : 0;
  return ld * 9 + lh * 3 + lw;
}

// ---------- weight transpose + bf16 convert: src f32 [K][N] -> dst bf16 [N][K] ----------
__global__ __launch_bounds__(256) void transpose_w(const float* __restrict__ src, u16* __restrict__ dst,
                                                   int K, int N) {
  __shared__ u16 t[32][33];
  int kt = blockIdx.x * 32, nt = blockIdx.y * 32;
  int lx = threadIdx.x & 31, ly = threadIdx.x >> 5;   // 8 rows/pass
#pragma unroll
  for (int i = 0; i < 32; i += 8)
    t[ly + i][lx] = f2bf(src[(size_t)(kt + ly + i) * N + nt + lx]);
  __syncthreads();
#pragma unroll
  for (int i = 0; i < 32; i += 8)
    dst[(size_t)(nt + ly + i) * K + kt + lx] = t[lx][ly + i];
}

__global__ __launch_bounds__(256) void bias_kernel(const float* __restrict__ rpb, float* __restrict__ biasb) {
  int i = blockIdx.x * 256 + threadIdx.x;   // 49152 = 12*64*64, layout [h][n][m]
  int h = i >> 12, n = (i >> 6) & 63, m = i & 63;
  int dd = (n >> 4) - (m >> 4) + 3;
  int dh = ((n >> 2) & 3) - ((m >> 2) & 3) + 3;
  int dw = (n & 3) - (m & 3) + 3;
  biasb[i] = rpb[(dd * 49 + dh * 7 + dw) * 12 + h];
}

// ---------- LayerNorm (one wave per token row) ----------
template<bool MAP>
__global__ __launch_bounds__(256) void ln_kernel(const float* __restrict__ x, const float* __restrict__ g,
                                                 const float* __restrict__ bta, u16* __restrict__ out) {
  int wid = threadIdx.x >> 6, lane = threadIdx.x & 63;
  int r = blockIdx.x * 4 + wid;
  int t = MAP ? row_to_token(r) : r;
  const float* src = x + (size_t)t * 384;
  float v[6]; float s = 0.f;
#pragma unroll
  for (int i = 0; i < 6; i++) { v[i] = src[lane + i * 64]; s += v[i]; }
#pragma unroll
  for (int off = 1; off < 64; off <<= 1) s += __shfl_xor(s, off);
  float mu = s * (1.f / 384.f);
  float vs = 0.f;
#pragma unroll
  for (int i = 0; i < 6; i++) { float d = v[i] - mu; vs += d * d; }
#pragma unroll
  for (int off = 1; off < 64; off <<= 1) vs += __shfl_xor(vs, off);
  float rstd = 1.f / sqrtf(vs * (1.f / 384.f) + 1e-5f);
  u16* dst = out + (size_t)r * 384;
#pragma unroll
  for (int i = 0; i < 6; i++) {
    int c = lane + i * 64;
    dst[c] = f2bf((v[i] - mu) * rstd * g[c] + bta[c]);
  }
}

// ---------- GEMM: 128x128 tile, BK=32, 4 waves, 16x16x32 bf16 MFMA ----------
// m97-style staging: global_load_lds width-16 into LINEAR LDS; 16B-slot XOR
// swizzle (phys_slot = slot ^ ((row>>1)&3)) applied to BOTH the global source
// and the ds_read side -> conflict-free ds_read_b128 (rule 21 involution).
// 1-D grid with bijective XCD swizzle (all nwg are multiples of 8).
// A: [M][K] bf16.  Bw: [N][K] bf16 (pre-transposed).
// EPI: 0=qkv(bias->bf16)  1=proj(bias + scatter + shortcut -> f32 out)
//      2=fc1(bias+gelu->bf16)  3=fc2(bias, += out f32)
template<int EPI>
__global__ __launch_bounds__(256) void gemm_bf16(const u16* __restrict__ A, const u16* __restrict__ Bw,
                                                 const float* __restrict__ bias, int N, int K,
                                                 u16* __restrict__ out_bf, float* __restrict__ out_f,
                                                 const float* __restrict__ resid, int ntn) {
  __shared__ __align__(16) u16 As[4096];   // 128 rows x 32 cols, slot-swizzled
  __shared__ __align__(16) u16 Bs[4096];
  const int tid = threadIdx.x;
  const int nwg = gridDim.x;
  const int bid = blockIdx.x;
  const int swz = (bid & 7) * (nwg >> 3) + (bid >> 3);   // XCD-chunked, bijective (nwg%8==0)
  const int by = swz / ntn;
  const int bx = swz - by * ntn;
  const int m0 = by * 128, n0 = bx * 128;
  const int wid = tid >> 6, lane = tid & 63;
  const int wm = (wid >> 1) * 64, wn = (wid & 1) * 64;
  const int l15 = lane & 15, q4 = lane >> 4;

  // staging: round i covers phys LDS bytes [i*4096 + tid*16, +16)
  // u = i*256 + tid; phys row = u>>2; logical slot = (u&3) ^ ((row>>1)&3)
  const int u0 = tid, u1 = 256 + tid;
  const int r0 = u0 >> 2, r1 = u1 >> 2;
  const int c0 = ((u0 & 3) ^ ((r0 >> 1) & 3)) << 3;   // u16 col offset
  const int c1 = ((u1 & 3) ^ ((r1 >> 1) & 3)) << 3;
  const u16* ag0 = A + (size_t)(m0 + r0) * K + c0;
  const u16* ag1 = A + (size_t)(m0 + r1) * K + c1;
  const u16* bg0 = Bw + (size_t)(n0 + r0) * K + c0;
  const u16* bg1 = Bw + (size_t)(n0 + r1) * K + c1;
  u16* asd0 = As + (wid << 9);          // wave-uniform LDS dests (1KB/wave/round)
  u16* asd1 = As + 2048 + (wid << 9);
  u16* bsd0 = Bs + (wid << 9);
  u16* bsd1 = Bs + 2048 + (wid << 9);

  // swizzled fragment-read byte offsets
  int aoff[4], boff[4];
#pragma unroll
  for (int t = 0; t < 4; t++) {
    int ra = wm + t * 16 + l15;
    aoff[t] = ra * 64 + ((q4 ^ ((ra >> 1) & 3)) << 4);
    int rb = wn + t * 16 + l15;
    boff[t] = rb * 64 + ((q4 ^ ((rb >> 1) & 3)) << 4);
  }

  v4f acc[4][4];
#pragma unroll
  for (int i = 0; i < 4; i++)
#pragma unroll
    for (int j = 0; j < 4; j++) acc[i][j] = (v4f){0.f, 0.f, 0.f, 0.f};

  // prologue: stage k-tile 0
  gll16(ag0, asd0); gll16(ag1, asd1);
  gll16(bg0, bsd0); gll16(bg1, bsd1);
  ag0 += 32; ag1 += 32; bg0 += 32; bg1 += 32;

  const int nk = K >> 5;
  for (int kk = 0; kk < nk; ++kk) {
    __syncthreads();                       // staged tile visible (vmcnt drain)
    v8s afr[4], bfr[4];
#pragma unroll
    for (int t = 0; t < 4; t++) {
      afr[t] = *(const v8s*)((const char*)As + aoff[t]);
      bfr[t] = *(const v8s*)((const char*)Bs + boff[t]);
    }
    __syncthreads();                       // all waves done reading LDS
    if (kk + 1 < nk) {                     // stage next tile; lands during MFMA
      gll16(ag0, asd0); gll16(ag1, asd1);
      gll16(bg0, bsd0); gll16(bg1, bsd1);
      ag0 += 32; ag1 += 32; bg0 += 32; bg1 += 32;
    }
#pragma unroll
    for (int tm = 0; tm < 4; tm++)
#pragma unroll
      for (int tn = 0; tn < 4; tn++)
        acc[tm][tn] = __builtin_amdgcn_mfma_f32_16x16x32_bf16(afr[tm], bfr[tn], acc[tm][tn], 0, 0, 0);
  }

  // epilogue
  float bb[4]; int gc[4];
#pragma unroll
  for (int tn = 0; tn < 4; tn++) { gc[tn] = n0 + wn + tn * 16 + l15; bb[tn] = bias[gc[tn]]; }
#pragma unroll
  for (int tm = 0; tm < 4; tm++) {
#pragma unroll
    for (int r = 0; r < 4; r++) {
      const int grow = m0 + wm + tm * 16 + q4 * 4 + r;
      size_t rowbase;
      if constexpr (EPI == 1) rowbase = (size_t)row_to_token(grow) * 384;
      else rowbase = (size_t)grow * N;
#pragma unroll
      for (int tn = 0; tn < 4; tn++) {
        float val = acc[tm][tn][r] + bb[tn];
        if constexpr (EPI == 0) {
          out_bf[rowbase + gc[tn]] = f2bf(val);
        } else if constexpr (EPI == 2) {
          out_bf[rowbase + gc[tn]] = f2bf(fast_gelu(val));
        } else if constexpr (EPI == 1) {
          out_f[rowbase + gc[tn]] = resid[rowbase + gc[tn]] + val;
        } else {
          out_f[rowbase + gc[tn]] += val;
        }
      }
    }
  }
}

// ---------- attention: one wave per (window, head) ----------
__global__ __launch_bounds__(256) void attn_kernel(const u16* __restrict__ qkv, const float* __restrict__ biasb,
                                                   u16* __restrict__ outb) {
  __shared__ u16 P[4][64][72];              // per-wave P tile, bf16, padded
  int wid = threadIdx.x >> 6, lane = threadIdx.x & 63;
  int g = blockIdx.x * 4 + wid;
  int win = g / 12, head = g - win * 12;
  int l15 = lane & 15, q4 = lane >> 4;
  const u16* base = qkv + (size_t)win * 64 * 1152;
  const u16* qp = base + head * 32;
  const u16* kp = base + 384 + head * 32;
  const u16* vp = base + 768 + head * 32;

  v8s a[4], kb[4];
#pragma unroll
  for (int tm = 0; tm < 4; tm++) a[tm] = *(const v8s*)(qp + (size_t)(tm * 16 + l15) * 1152 + q4 * 8);
#pragma unroll
  for (int tn = 0; tn < 4; tn++) kb[tn] = *(const v8s*)(kp + (size_t)(tn * 16 + l15) * 1152 + q4 * 8);
  v4f acc[4][4];
#pragma unroll
  for (int i = 0; i < 4; i++)
#pragma unroll
    for (int j = 0; j < 4; j++) acc[i][j] = (v4f){0.f, 0.f, 0.f, 0.f};
#pragma unroll
  for (int tm = 0; tm < 4; tm++)
#pragma unroll
    for (int tn = 0; tn < 4; tn++)
      acc[tm][tn] = __builtin_amdgcn_mfma_f32_16x16x32_bf16(a[tm], kb[tn], acc[tm][tn], 0, 0, 0);

  int wrem = win % 784;
  int wd = wrem / 196, r2 = wrem % 196, wh = r2 / 14, ww = r2 % 14;
  int bd = (wd == 3), bh = (wh == 13), bw = (ww == 13);
  const float* bptr = biasb + head * 4096;
  int mlab[4];
#pragma unroll
  for (int tn = 0; tn < 4; tn++) mlab[tn] = region_label(tn * 16 + l15, bd, bh, bw);

#pragma unroll
  for (int tm = 0; tm < 4; tm++) {
#pragma unroll
    for (int r = 0; r < 4; r++) {
      int n = tm * 16 + q4 * 4 + r;
      int nlab = region_label(n, bd, bh, bw);
      float sv[4];
      float mx = -1e30f;
#pragma unroll
      for (int tn = 0; tn < 4; tn++) {
        int m = tn * 16 + l15;
        float s = acc[tm][tn][r] * 0.17677669529663687f + bptr[n * 64 + m];
        if (mlab[tn] != nlab) s -= 100.f;
        sv[tn] = s;
        mx = fmaxf(mx, s);
      }
#pragma unroll
      for (int off = 1; off < 16; off <<= 1) mx = fmaxf(mx, __shfl_xor(mx, off));
      float sum = 0.f;
#pragma unroll
      for (int tn = 0; tn < 4; tn++) { float e = __expf(sv[tn] - mx); sv[tn] = e; sum += e; }
#pragma unroll
      for (int off = 1; off < 16; off <<= 1) sum += __shfl_xor(sum, off);
      float inv = 1.f / sum;
#pragma unroll
      for (int tn = 0; tn < 4; tn++) P[wid][n][tn * 16 + l15] = f2bf(sv[tn] * inv);
    }
  }
  __syncthreads();   // C-layout -> A-layout via LDS

  v4f o[4][2];
#pragma unroll
  for (int i = 0; i < 4; i++) { o[i][0] = (v4f){0.f,0.f,0.f,0.f}; o[i][1] = (v4f){0.f,0.f,0.f,0.f}; }
#pragma unroll
  for (int kt = 0; kt < 2; kt++) {
    v8s pa[4];
#pragma unroll
    for (int tm = 0; tm < 4; tm++) pa[tm] = *(const v8s*)&P[wid][tm * 16 + l15][kt * 32 + q4 * 8];
#pragma unroll
    for (int tn = 0; tn < 2; tn++) {
      v8s vb;
#pragma unroll
      for (int j = 0; j < 8; j++) vb[j] = (short)vp[(size_t)(kt * 32 + q4 * 8 + j) * 1152 + tn * 16 + l15];
#pragma unroll
      for (int tm = 0; tm < 4; tm++)
        o[tm][tn] = __builtin_amdgcn_mfma_f32_16x16x32_bf16(pa[tm], vb, o[tm][tn], 0, 0, 0);
    }
  }
#pragma unroll
  for (int tm = 0; tm < 4; tm++)
#pragma unroll
    for (int tn = 0; tn < 2; tn++)
#pragma unroll
      for (int r = 0; r < 4; r++) {
        int n = tm * 16 + q4 * 4 + r;
        outb[(size_t)(win * 64 + n) * 384 + head * 32 + tn * 16 + l15] = f2bf(o[tm][tn][r]);
      }
}

// ---------- launch ----------
extern "C" void kernel_launch(void* const* d_in, const int* in_sizes, int n_in,
                              void* d_out, int out_size, void* d_ws, size_t ws_size,
                              hipStream_t stream) {
  const float* x      = (const float*)d_in[0];
  const float* n1g    = (const float*)d_in[1];
  const float* n1b    = (const float*)d_in[2];
  const float* qkv_w  = (const float*)d_in[3];
  const float* qkv_b  = (const float*)d_in[4];
  const float* rpb    = (const float*)d_in[5];
  const float* proj_w = (const float*)d_in[6];
  const float* proj_b = (const float*)d_in[7];
  const float* n2g    = (const float*)d_in[8];
  const float* n2b    = (const float*)d_in[9];
  const float* fc1_w  = (const float*)d_in[10];
  const float* fc1_b  = (const float*)d_in[11];
  const float* fc2_w  = (const float*)d_in[12];
  const float* fc2_b  = (const float*)d_in[13];
  float* out = (float*)d_out;
  char* ws = (char*)d_ws;

  // workspace layout (bytes): weights_bf16(T) | attn_bias | lnbuf | [qkv | attn_out] / fc1_out
  u16*   wb    = (u16*)ws;                        // 1769472 el
  float* biasb = (float*)(ws + 3538944);          // 49152 f32
  u16*   lnbuf = (u16*)(ws + 3735552);            // 100352*384
  u16*   qkvb  = (u16*)(ws + 80805888);           // 100352*1152
  u16*   attnb = (u16*)(ws + 312016896);          // 100352*384
  u16*   fc1ob = (u16*)(ws + 80805888);           // 100352*1536 (aliases dead qkvb+attnb)

  u16* qkv_wt  = wb;                  // [1152][384]
  u16* proj_wt = wb + 442368;         // [384][384]
  u16* fc1_wt  = wb + 589824;         // [1536][384]
  u16* fc2_wt  = wb + 1179648;        // [384][1536]

  transpose_w<<<dim3(12, 36), 256, 0, stream>>>(qkv_w,  qkv_wt,  384, 1152);
  transpose_w<<<dim3(12, 12), 256, 0, stream>>>(proj_w, proj_wt, 384, 384);
  transpose_w<<<dim3(12, 48), 256, 0, stream>>>(fc1_w,  fc1_wt,  384, 1536);
  transpose_w<<<dim3(48, 12), 256, 0, stream>>>(fc2_w,  fc2_wt,  1536, 384);
  bias_kernel<<<192, 256, 0, stream>>>(rpb, biasb);
  ln_kernel<true><<<25088, 256, 0, stream>>>(x, n1g, n1b, lnbuf);
  gemm_bf16<0><<<dim3(9 * 784), 256, 0, stream>>>(lnbuf, qkv_wt, qkv_b, 1152, 384, qkvb, nullptr, nullptr, 9);
  attn_kernel<<<4704, 256, 0, stream>>>(qkvb, biasb, attnb);
  gemm_bf16<1><<<dim3(3 * 784), 256, 0, stream>>>(attnb, proj_wt, proj_b, 384, 384, nullptr, out, x, 3);
  ln_kernel<false><<<25088, 256, 0, stream>>>(out, n2g, n2b, lnbuf);
  gemm_bf16<2><<<dim3(12 * 784), 256, 0, stream>>>(lnbuf, fc1_wt, fc1_b, 1536, 384, fc1ob, nullptr, nullptr, 12);
  gemm_bf16<3><<<dim3(3 * 784), 256, 0, stream>>>(fc1ob, fc2_wt, fc2_b, 384, 1536, nullptr, out, nullptr, 3);
}

// Round 3
// 1081.639 us; speedup vs baseline: 1.1257x; 1.0010x over previous
//
#include <hip/hip_runtime.h>
#include <math.h>

typedef unsigned short u16;
typedef float v4f __attribute__((ext_vector_type(4)));
typedef short v8s __attribute__((ext_vector_type(8)));

// ---------- helpers ----------
__device__ __forceinline__ u16 f2bf(float f) {
  union { float f; unsigned u; } c; c.f = f;
  unsigned u = c.u;
  u += 0x7fff + ((u >> 16) & 1);   // RNE
  return (u16)(u >> 16);
}

// fast GELU: x * sigmoid(2c(x + 0.044715 x^3)), c = sqrt(2/pi), via exp2/rcp HW units.
__device__ __forceinline__ float fast_gelu(float x) {
  float t = x * x;
  float u = x * (2.3022082f + 0.10294325f * t);
  float e = __builtin_amdgcn_exp2f(-u);
  return x * __builtin_amdgcn_rcpf(1.f + e);
}

// async global->LDS, 16B per lane, dest = wave-uniform base + lane*16
typedef __attribute__((address_space(1))) const unsigned int guint;
typedef __attribute__((address_space(3))) unsigned int luint;
__device__ __forceinline__ void gll16(const void* g, void* l) {
  __builtin_amdgcn_global_load_lds((guint*)g, (luint*)l, 16, 0, 0);
}

// window-row r (win*64+n, shifted frame) -> natural token index.
__device__ __forceinline__ int row_to_token(int r) {
  int win = r >> 6, n = r & 63;
  int b = (win >= 784) ? 1 : 0;
  int wrem = win - b * 784;
  int wd = wrem / 196;
  int r2 = wrem - wd * 196;
  int wh = r2 / 14;
  int ww = r2 - wh * 14;
  int d = wd * 4 + (n >> 4);
  int h = wh * 4 + ((n >> 2) & 3);
  int w = ww * 4 + (n & 3);
  d = (d + 2) & 15;
  h += 2; if (h >= 56) h -= 56;
  w += 2; if (w >= 56) w -= 56;
  return ((b * 16 + d) * 56 + h) * 56 + w;
}

__device__ __forceinline__ int region_label(int n, int bd, int bh, int bw) {
  int ld = bd ? (((n >> 4) >= 2) ? 2 : 1) : 0;
  int lh = bh ? ((((n >> 2) & 3) >= 2) ? 2 : 1) : 0;
  int lw = bw ? (((n & 3) >= 2) ? 2 : 1) : 0;
  return ld * 9 + lh * 3 + lw;
}

// ---------- weight transpose + bf16 convert: src f32 [K][N] -> dst bf16 [N][K] ----------
__global__ __launch_bounds__(256) void transpose_w(const float* __restrict__ src, u16* __restrict__ dst,
                                                   int K, int N) {
  __shared__ u16 t[32][33];
  int kt = blockIdx.x * 32, nt = blockIdx.y * 32;
  int lx = threadIdx.x & 31, ly = threadIdx.x >> 5;   // 8 rows/pass
#pragma unroll
  for (int i = 0; i < 32; i += 8)
    t[ly + i][lx] = f2bf(src[(size_t)(kt + ly + i) * N + nt + lx]);
  __syncthreads();
#pragma unroll
  for (int i = 0; i < 32; i += 8)
    dst[(size_t)(nt + ly + i) * K + kt + lx] = t[lx][ly + i];
}

__global__ __launch_bounds__(256) void bias_kernel(const float* __restrict__ rpb, float* __restrict__ biasb) {
  int i = blockIdx.x * 256 + threadIdx.x;   // 49152 = 12*64*64, layout [h][n][m]
  int h = i >> 12, n = (i >> 6) & 63, m = i & 63;
  int dd = (n >> 4) - (m >> 4) + 3;
  int dh = ((n >> 2) & 3) - ((m >> 2) & 3) + 3;
  int dw = (n & 3) - (m & 3) + 3;
  biasb[i] = rpb[(dd * 49 + dh * 7 + dw) * 12 + h];
}

// ---------- LayerNorm (one wave per token row) ----------
template<bool MAP>
__global__ __launch_bounds__(256) void ln_kernel(const float* __restrict__ x, const float* __restrict__ g,
                                                 const float* __restrict__ bta, u16* __restrict__ out) {
  int wid = threadIdx.x >> 6, lane = threadIdx.x & 63;
  int r = blockIdx.x * 4 + wid;
  int t = MAP ? row_to_token(r) : r;
  const float* src = x + (size_t)t * 384;
  float v[6]; float s = 0.f;
#pragma unroll
  for (int i = 0; i < 6; i++) { v[i] = src[lane + i * 64]; s += v[i]; }
#pragma unroll
  for (int off = 1; off < 64; off <<= 1) s += __shfl_xor(s, off);
  float mu = s * (1.f / 384.f);
  float vs = 0.f;
#pragma unroll
  for (int i = 0; i < 6; i++) { float d = v[i] - mu; vs += d * d; }
#pragma unroll
  for (int off = 1; off < 64; off <<= 1) vs += __shfl_xor(vs, off);
  float rstd = 1.f / sqrtf(vs * (1.f / 384.f) + 1e-5f);
  u16* dst = out + (size_t)r * 384;
#pragma unroll
  for (int i = 0; i < 6; i++) {
    int c = lane + i * 64;
    dst[c] = f2bf((v[i] - mu) * rstd * g[c] + bta[c]);
  }
}

// ---------- GEMM: 128x128 tile, BK=32, 4 waves, 16x16x32 bf16 MFMA ----------
// T4 counted-vmcnt pipeline: 2-deep LDS double-buffer; iteration kk waits
// vmcnt(4) (tile kk landed, tile kk+1 stays IN FLIGHT across the barrier),
// reads buf kk&1, lgkmcnt(0)+barrier, then stages tile kk+2 into the
// just-read buffer. Raw s_barrier + inline-asm waits (no implicit vmcnt(0)
// drain). LDS swizzle: phys_slot = slot ^ ((row>>1)&3) on BOTH global source
// and ds_read side (rule 21 involution) -> conflict-free ds_read_b128.
// 1-D grid with bijective XCD swizzle (all nwg are multiples of 8).
// A: [M][K] bf16.  Bw: [N][K] bf16 (pre-transposed).
// EPI: 0=qkv(bias->bf16)  1=proj(bias + scatter + shortcut -> f32 out)
//      2=fc1(bias+gelu->bf16)  3=fc2(bias, += out f32)
template<int EPI>
__global__ __launch_bounds__(256) void gemm_bf16(const u16* __restrict__ A, const u16* __restrict__ Bw,
                                                 const float* __restrict__ bias, int N, int K,
                                                 u16* __restrict__ out_bf, float* __restrict__ out_f,
                                                 const float* __restrict__ resid, int ntn) {
  __shared__ __align__(16) u16 As[2][4096];   // 128 rows x 32 cols, slot-swizzled, 2 buffers
  __shared__ __align__(16) u16 Bs[2][4096];
  const int tid = threadIdx.x;
  const int nwg = gridDim.x;
  const int bid = blockIdx.x;
  const int swz = (bid & 7) * (nwg >> 3) + (bid >> 3);   // XCD-chunked, bijective (nwg%8==0)
  const int by = swz / ntn;
  const int bx = swz - by * ntn;
  const int m0 = by * 128, n0 = bx * 128;
  const int wid = tid >> 6, lane = tid & 63;
  const int wm = (wid >> 1) * 64, wn = (wid & 1) * 64;
  const int l15 = lane & 15, q4 = lane >> 4;

  // staging: round i covers phys LDS bytes [i*4096 + tid*16, +16) of a buffer
  // u = i*256 + tid; phys row = u>>2; logical slot = (u&3) ^ ((row>>1)&3)
  const int u0 = tid, u1 = 256 + tid;
  const int r0 = u0 >> 2, r1 = u1 >> 2;
  const int c0 = ((u0 & 3) ^ ((r0 >> 1) & 3)) << 3;   // u16 col offset
  const int c1 = ((u1 & 3) ^ ((r1 >> 1) & 3)) << 3;
  const u16* ag0 = A + (size_t)(m0 + r0) * K + c0;
  const u16* ag1 = A + (size_t)(m0 + r1) * K + c1;
  const u16* bg0 = Bw + (size_t)(n0 + r0) * K + c0;
  const u16* bg1 = Bw + (size_t)(n0 + r1) * K + c1;
  const int wofs = wid << 9;   // wave-uniform LDS dest offset (1KB/wave/round)

  // swizzled fragment-read byte offsets (within one 8KB buffer)
  int aoff[4], boff[4];
#pragma unroll
  for (int t = 0; t < 4; t++) {
    int ra = wm + t * 16 + l15;
    aoff[t] = ra * 64 + ((q4 ^ ((ra >> 1) & 3)) << 4);
    int rb = wn + t * 16 + l15;
    boff[t] = rb * 64 + ((q4 ^ ((rb >> 1) & 3)) << 4);
  }

  v4f acc[4][4];
#pragma unroll
  for (int i = 0; i < 4; i++)
#pragma unroll
    for (int j = 0; j < 4; j++) acc[i][j] = (v4f){0.f, 0.f, 0.f, 0.f};

  const int nk = K >> 5;   // always >= 2 here (K in {384,1536})

  // prologue: stage tile 0 -> buf 0, tile 1 -> buf 1   (8 loads outstanding)
  gll16(ag0, &As[0][wofs]); gll16(ag1, &As[0][2048 + wofs]);
  gll16(bg0, &Bs[0][wofs]); gll16(bg1, &Bs[0][2048 + wofs]);
  ag0 += 32; ag1 += 32; bg0 += 32; bg1 += 32;
  gll16(ag0, &As[1][wofs]); gll16(ag1, &As[1][2048 + wofs]);
  gll16(bg0, &Bs[1][wofs]); gll16(bg1, &Bs[1][2048 + wofs]);
  ag0 += 32; ag1 += 32; bg0 += 32; bg1 += 32;

  for (int kk = 0; kk < nk - 1; ++kk) {
    // tile kk's 4 loads done; tile kk+1's 4 remain in flight across the barrier
    asm volatile("s_waitcnt vmcnt(4)" ::: "memory");
    __builtin_amdgcn_s_barrier();
    __builtin_amdgcn_sched_barrier(0);
    const int b = kk & 1;
    v8s afr[4], bfr[4];
#pragma unroll
    for (int t = 0; t < 4; t++) {
      afr[t] = *(const v8s*)((const char*)&As[b][0] + aoff[t]);
      bfr[t] = *(const v8s*)((const char*)&Bs[b][0] + boff[t]);
    }
    asm volatile("s_waitcnt lgkmcnt(0)" ::: "memory");   // reads landed in regs
    __builtin_amdgcn_sched_barrier(0);
    __builtin_amdgcn_s_barrier();                        // all waves done reading buf b
    __builtin_amdgcn_sched_barrier(0);
    asm volatile("" ::: "memory");
    if (kk + 2 < nk) {                                   // stage tile kk+2 into buf b
      gll16(ag0, &As[b][wofs]); gll16(ag1, &As[b][2048 + wofs]);
      gll16(bg0, &Bs[b][wofs]); gll16(bg1, &Bs[b][2048 + wofs]);
      ag0 += 32; ag1 += 32; bg0 += 32; bg1 += 32;
    }
#pragma unroll
    for (int tm = 0; tm < 4; tm++)
#pragma unroll
      for (int tn = 0; tn < 4; tn++)
        acc[tm][tn] = __builtin_amdgcn_mfma_f32_16x16x32_bf16(afr[tm], bfr[tn], acc[tm][tn], 0, 0, 0);
  }
  {  // peeled final iteration: only tile nk-1 outstanding
    asm volatile("s_waitcnt vmcnt(0)" ::: "memory");
    __builtin_amdgcn_s_barrier();
    __builtin_amdgcn_sched_barrier(0);
    const int b = (nk - 1) & 1;
    v8s afr[4], bfr[4];
#pragma unroll
    for (int t = 0; t < 4; t++) {
      afr[t] = *(const v8s*)((const char*)&As[b][0] + aoff[t]);
      bfr[t] = *(const v8s*)((const char*)&Bs[b][0] + boff[t]);
    }
#pragma unroll
    for (int tm = 0; tm < 4; tm++)
#pragma unroll
      for (int tn = 0; tn < 4; tn++)
        acc[tm][tn] = __builtin_amdgcn_mfma_f32_16x16x32_bf16(afr[tm], bfr[tn], acc[tm][tn], 0, 0, 0);
  }

  // epilogue
  float bb[4]; int gc[4];
#pragma unroll
  for (int tn = 0; tn < 4; tn++) { gc[tn] = n0 + wn + tn * 16 + l15; bb[tn] = bias[gc[tn]]; }
#pragma unroll
  for (int tm = 0; tm < 4; tm++) {
#pragma unroll
    for (int r = 0; r < 4; r++) {
      const int grow = m0 + wm + tm * 16 + q4 * 4 + r;
      size_t rowbase;
      if constexpr (EPI == 1) rowbase = (size_t)row_to_token(grow) * 384;
      else rowbase = (size_t)grow * N;
#pragma unroll
      for (int tn = 0; tn < 4; tn++) {
        float val = acc[tm][tn][r] + bb[tn];
        if constexpr (EPI == 0) {
          out_bf[rowbase + gc[tn]] = f2bf(val);
        } else if constexpr (EPI == 2) {
          out_bf[rowbase + gc[tn]] = f2bf(fast_gelu(val));
        } else if constexpr (EPI == 1) {
          out_f[rowbase + gc[tn]] = resid[rowbase + gc[tn]] + val;
        } else {
          out_f[rowbase + gc[tn]] += val;
        }
      }
    }
  }
}

// ---------- attention: one wave per (window, head) ----------
__global__ __launch_bounds__(256) void attn_kernel(const u16* __restrict__ qkv, const float* __restrict__ biasb,
                                                   u16* __restrict__ outb) {
  __shared__ u16 P[4][64][72];              // per-wave P tile, bf16, padded
  int wid = threadIdx.x >> 6, lane = threadIdx.x & 63;
  int g = blockIdx.x * 4 + wid;
  int win = g / 12, head = g - win * 12;
  int l15 = lane & 15, q4 = lane >> 4;
  const u16* base = qkv + (size_t)win * 64 * 1152;
  const u16* qp = base + head * 32;
  const u16* kp = base + 384 + head * 32;
  const u16* vp = base + 768 + head * 32;

  v8s a[4], kb[4];
#pragma unroll
  for (int tm = 0; tm < 4; tm++) a[tm] = *(const v8s*)(qp + (size_t)(tm * 16 + l15) * 1152 + q4 * 8);
#pragma unroll
  for (int tn = 0; tn < 4; tn++) kb[tn] = *(const v8s*)(kp + (size_t)(tn * 16 + l15) * 1152 + q4 * 8);
  v4f acc[4][4];
#pragma unroll
  for (int i = 0; i < 4; i++)
#pragma unroll
    for (int j = 0; j < 4; j++) acc[i][j] = (v4f){0.f, 0.f, 0.f, 0.f};
#pragma unroll
  for (int tm = 0; tm < 4; tm++)
#pragma unroll
    for (int tn = 0; tn < 4; tn++)
      acc[tm][tn] = __builtin_amdgcn_mfma_f32_16x16x32_bf16(a[tm], kb[tn], acc[tm][tn], 0, 0, 0);

  int wrem = win % 784;
  int wd = wrem / 196, r2 = wrem % 196, wh = r2 / 14, ww = r2 % 14;
  int bd = (wd == 3), bh = (wh == 13), bw = (ww == 13);
  const float* bptr = biasb + head * 4096;
  int mlab[4];
#pragma unroll
  for (int tn = 0; tn < 4; tn++) mlab[tn] = region_label(tn * 16 + l15, bd, bh, bw);

#pragma unroll
  for (int tm = 0; tm < 4; tm++) {
#pragma unroll
    for (int r = 0; r < 4; r++) {
      int n = tm * 16 + q4 * 4 + r;
      int nlab = region_label(n, bd, bh, bw);
      float sv[4];
      float mx = -1e30f;
#pragma unroll
      for (int tn = 0; tn < 4; tn++) {
        int m = tn * 16 + l15;
        float s = acc[tm][tn][r] * 0.17677669529663687f + bptr[n * 64 + m];
        if (mlab[tn] != nlab) s -= 100.f;
        sv[tn] = s;
        mx = fmaxf(mx, s);
      }
#pragma unroll
      for (int off = 1; off < 16; off <<= 1) mx = fmaxf(mx, __shfl_xor(mx, off));
      float sum = 0.f;
#pragma unroll
      for (int tn = 0; tn < 4; tn++) { float e = __expf(sv[tn] - mx); sv[tn] = e; sum += e; }
#pragma unroll
      for (int off = 1; off < 16; off <<= 1) sum += __shfl_xor(sum, off);
      float inv = 1.f / sum;
#pragma unroll
      for (int tn = 0; tn < 4; tn++) P[wid][n][tn * 16 + l15] = f2bf(sv[tn] * inv);
    }
  }
  __syncthreads();   // C-layout -> A-layout via LDS

  v4f o[4][2];
#pragma unroll
  for (int i = 0; i < 4; i++) { o[i][0] = (v4f){0.f,0.f,0.f,0.f}; o[i][1] = (v4f){0.f,0.f,0.f,0.f}; }
#pragma unroll
  for (int kt = 0; kt < 2; kt++) {
    v8s pa[4];
#pragma unroll
    for (int tm = 0; tm < 4; tm++) pa[tm] = *(const v8s*)&P[wid][tm * 16 + l15][kt * 32 + q4 * 8];
#pragma unroll
    for (int tn = 0; tn < 2; tn++) {
      v8s vb;
#pragma unroll
      for (int j = 0; j < 8; j++) vb[j] = (short)vp[(size_t)(kt * 32 + q4 * 8 + j) * 1152 + tn * 16 + l15];
#pragma unroll
      for (int tm = 0; tm < 4; tm++)
        o[tm][tn] = __builtin_amdgcn_mfma_f32_16x16x32_bf16(pa[tm], vb, o[tm][tn], 0, 0, 0);
    }
  }
#pragma unroll
  for (int tm = 0; tm < 4; tm++)
#pragma unroll
    for (int tn = 0; tn < 2; tn++)
#pragma unroll
      for (int r = 0; r < 4; r++) {
        int n = tm * 16 + q4 * 4 + r;
        outb[(size_t)(win * 64 + n) * 384 + head * 32 + tn * 16 + l15] = f2bf(o[tm][tn][r]);
      }
}

// ---------- launch ----------
extern "C" void kernel_launch(void* const* d_in, const int* in_sizes, int n_in,
                              void* d_out, int out_size, void* d_ws, size_t ws_size,
                              hipStream_t stream) {
  const float* x      = (const float*)d_in[0];
  const float* n1g    = (const float*)d_in[1];
  const float* n1b    = (const float*)d_in[2];
  const float* qkv_w  = (const float*)d_in[3];
  const float* qkv_b  = (const float*)d_in[4];
  const float* rpb    = (const float*)d_in[5];
  const float* proj_w = (const float*)d_in[6];
  const float* proj_b = (const float*)d_in[7];
  const float* n2g    = (const float*)d_in[8];
  const float* n2b    = (const float*)d_in[9];
  const float* fc1_w  = (const float*)d_in[10];
  const float* fc1_b  = (const float*)d_in[11];
  const float* fc2_w  = (const float*)d_in[12];
  const float* fc2_b  = (const float*)d_in[13];
  float* out = (float*)d_out;
  char* ws = (char*)d_ws;

  // workspace layout (bytes): weights_bf16(T) | attn_bias | lnbuf | [qkv | attn_out] / fc1_out
  u16*   wb    = (u16*)ws;                        // 1769472 el
  float* biasb = (float*)(ws + 3538944);          // 49152 f32
  u16*   lnbuf = (u16*)(ws + 3735552);            // 100352*384
  u16*   qkvb  = (u16*)(ws + 80805888);           // 100352*1152
  u16*   attnb = (u16*)(ws + 312016896);          // 100352*384
  u16*   fc1ob = (u16*)(ws + 80805888);           // 100352*1536 (aliases dead qkvb+attnb)

  u16* qkv_wt  = wb;                  // [1152][384]
  u16* proj_wt = wb + 442368;         // [384][384]
  u16* fc1_wt  = wb + 589824;         // [1536][384]
  u16* fc2_wt  = wb + 1179648;        // [384][1536]

  transpose_w<<<dim3(12, 36), 256, 0, stream>>>(qkv_w,  qkv_wt,  384, 1152);
  transpose_w<<<dim3(12, 12), 256, 0, stream>>>(proj_w, proj_wt, 384, 384);
  transpose_w<<<dim3(12, 48), 256, 0, stream>>>(fc1_w,  fc1_wt,  384, 1536);
  transpose_w<<<dim3(48, 12), 256, 0, stream>>>(fc2_w,  fc2_wt,  1536, 384);
  bias_kernel<<<192, 256, 0, stream>>>(rpb, biasb);
  ln_kernel<true><<<25088, 256, 0, stream>>>(x, n1g, n1b, lnbuf);
  gemm_bf16<0><<<dim3(9 * 784), 256, 0, stream>>>(lnbuf, qkv_wt, qkv_b, 1152, 384, qkvb, nullptr, nullptr, 9);
  attn_kernel<<<4704, 256, 0, stream>>>(qkvb, biasb, attnb);
  gemm_bf16<1><<<dim3(3 * 784), 256, 0, stream>>>(attnb, proj_wt, proj_b, 384, 384, nullptr, out, x, 3);
  ln_kernel<false><<<25088, 256, 0, stream>>>(out, n2g, n2b, lnbuf);
  gemm_bf16<2><<<dim3(12 * 784), 256, 0, stream>>>(lnbuf, fc1_wt, fc1_b, 1536, 384, fc1ob, nullptr, nullptr, 12);
  gemm_bf16<3><<<dim3(3 * 784), 256, 0, stream>>>(fc1ob, fc2_wt, fc2_b, 384, 1536, nullptr, out, nullptr, 3);
}